// Round 13
// baseline (286.565 us; speedup 1.0000x reference)
//
#include <hip/hip_runtime.h>
#include <stdint.h>

#define N_NODES 50000
#define N_EDGES 1600000
#define HID 128
#define NB 196      // dst buckets of 256 nodes
#define CHUNK 8192
#define NCH 196     // ceil(1600000 / 8192)
#define TOT (NB * NCH)
#define NGB 6250    // gather_h0 blocks (N*32/256)
#define NCW 1152    // convert_w blocks
#define NMB 782     // gemm 64-row tiles

typedef float f32x4 __attribute__((ext_vector_type(4)));
typedef float f32x2 __attribute__((ext_vector_type(2)));
typedef short s16x8 __attribute__((ext_vector_type(8)));
typedef unsigned u32x4 __attribute__((ext_vector_type(4)));
typedef unsigned u32x2 __attribute__((ext_vector_type(2)));

__device__ __forceinline__ unsigned short f2bf(float f) {
  unsigned u = __float_as_uint(f);
  u += 0x7fffu + ((u >> 16) & 1u);   // RNE
  return (unsigned short)(u >> 16);
}

__device__ __forceinline__ int block_scan_excl(int v, int t) {
  const int lane = t & 63, wid = t >> 6;
  int incl = v;
  #pragma unroll
  for (int o = 1; o < 64; o <<= 1) {
    int nv = __shfl_up(incl, o);
    if (lane >= o) incl += nv;
  }
  __shared__ int wsum[4];
  if (lane == 63) wsum[wid] = incl;
  __syncthreads();
  int wbase = 0;
  #pragma unroll
  for (int w = 0; w < 3; ++w) if (w < wid) wbase += wsum[w];
  return wbase + incl - v;
}

// ---- pre-kernel: gather_h0 | chunk_hist | convert_w ----
__global__ void k_pre(const int* __restrict__ nid, const float* __restrict__ emb,
                      unsigned short* __restrict__ h0,
                      const int* __restrict__ dst, int* __restrict__ histT,
                      const float* __restrict__ W, const float* __restrict__ Wl,
                      unsigned short* __restrict__ Wt) {
  const int bid = blockIdx.x, t = threadIdx.x;
  if (bid < NGB) {                       // h0 = bf16(emb[node_id])
    int g = bid * 256 + t;
    int i = g >> 5, c = (g & 31) * 4;
    const float4 v = *(const float4*)(emb + (size_t)nid[i] * HID + c);
    ushort4 o;
    o.x = f2bf(v.x); o.y = f2bf(v.y); o.z = f2bf(v.z); o.w = f2bf(v.w);
    *(ushort4*)(h0 + (size_t)i * HID + c) = o;
  } else if (bid < NGB + NCH) {          // per-chunk bucket histogram
    __shared__ int h[NB];
    const int c = bid - NGB;
    if (t < NB) h[t] = 0;
    __syncthreads();
    int base = c * CHUNK;
    #pragma unroll 4
    for (int i = t; i < CHUNK; i += 256) {
      int e = base + i;
      if (e < N_EDGES) atomicAdd(&h[dst[e] >> 8], 1);
    }
    __syncthreads();
    if (t < NB) histT[t * NCH + c] = h[t];
  } else {                               // Wt[l][r][k][d] = W[l][r][d][k]
    int idx = (bid - NGB - NCH) * 256 + t;
    int d  = idx & 127;
    int k  = (idx >> 7) & 127;
    int lr = idx >> 14;
    int l = lr / 9, r = lr - l * 9;
    float v;
    if (r < 8) v = W[((((size_t)l * 8 + r) * 128) + d) * 128 + k];
    else       v = Wl[(((size_t)l * 128) + d) * 128 + k];
    Wt[idx] = f2bf(v);
  }
}

// ---- CSR pass B1: per-bucket chunk-prefix scan (196 blocks, 1 wave each) ----
__global__ void k_scan_buckets(const int* __restrict__ histT, int* __restrict__ curL,
                               int* __restrict__ btot) {
  const int b = blockIdx.x, tid = threadIdx.x;   // 64 threads
  int carry = 0;
  #pragma unroll
  for (int k = 0; k < 4; ++k) {
    int c = k * 64 + tid;
    int v = (c < NCH) ? histT[b * NCH + c] : 0;
    int incl = v;
    #pragma unroll
    for (int o = 1; o < 64; o <<= 1) {
      int nv = __shfl_up(incl, o);
      if (tid >= o) incl += nv;
    }
    if (c < NCH) curL[b * NCH + c] = carry + incl - v;
    carry += __shfl(incl, 63);
  }
  if (tid == 0) btot[b] = carry;
}

// ---- CSR pass B2: scan 196 bucket totals -> bbase ----
__global__ void k_scan_top(const int* __restrict__ btot, int* __restrict__ bbase,
                           int* __restrict__ rowptr) {
  const int t = threadIdx.x;
  int v = (t < NB) ? btot[t] : 0;
  int ex = block_scan_excl(v, t);
  if (t < NB) bbase[t] = ex;
  if (t == 0) { bbase[NB] = N_EDGES; rowptr[N_NODES] = N_EDGES; }
}

// ---- GEMM (all 9 rels per mb-tile, A staged once) | optional scatter role ----
// X[rel][n][k] = sum_d A[n][d] * Wt[rel][k][d]   [round-10 proven structure]
template <bool SCAT>
__global__ __launch_bounds__(256, 3) void k_gemm9(
    const unsigned short* __restrict__ A,   // [N][128] bf16
    const unsigned short* __restrict__ Bw,  // [9][128][128] bf16 (this layer)
    unsigned short* __restrict__ X,         // [9][N][128] bf16
    const int* __restrict__ src, const int* __restrict__ dst,
    const int* __restrict__ et, const int* __restrict__ curL,
    const int* __restrict__ bbase, unsigned* __restrict__ tmp) {
  __shared__ unsigned char As[16384];   // 64 rows x 256B
  __shared__ unsigned char Ws[32768];   // 128 rows x 256B
  const int t = threadIdx.x;
  if (SCAT && blockIdx.x >= NMB) {      // chunk-local scatter role
    __shared__ int off2[NB];
    const int c = blockIdx.x - NMB;
    if (t < NB) off2[t] = curL[t * NCH + c] + bbase[t];
    __syncthreads();
    int base = c * CHUNK;
    #pragma unroll 4
    for (int i = t; i < CHUNK; i += 256) {
      int e = base + i;
      if (e < N_EDGES) {
        int d = dst[e];
        int pos = atomicAdd(&off2[d >> 8], 1);
        tmp[pos] = ((unsigned)(d & 255) << 19) | ((unsigned)et[e] << 16) | (unsigned)src[e];
      }
    }
    return;
  }
  const int mb = blockIdx.x;
  const int wid = t >> 6, lane = t & 63;
  const int lr = lane & 15, kg = (lane >> 4) * 8;
  // stage A-tile once (16KB), swizzled
  const unsigned char* Asrc = (const unsigned char*)A;
  #pragma unroll
  for (int c = 0; c < 4; ++c) {
    int off = c * 4096 + t * 16;
    int row = off >> 8, ib = off & 255;
    int grow = mb * 64 + row;
    u32x4 va = (u32x4)(0u);
    if (grow < N_NODES) va = *(const u32x4*)(Asrc + (size_t)grow * 256 + ib);
    *(u32x4*)(As + row * 256 + (ib ^ ((row & 7) << 4))) = va;
  }
  for (int rel = 0; rel < 9; ++rel) {
    // stage W_rel (32KB), swizzled
    const unsigned char* Bsrc = (const unsigned char*)(Bw + (size_t)rel * 16384);
    #pragma unroll
    for (int c = 0; c < 8; ++c) {
      int off = c * 4096 + t * 16;
      int row = off >> 8, ib = off & 255;
      *(u32x4*)(Ws + row * 256 + (ib ^ ((row & 7) << 4))) = *(const u32x4*)(Bsrc + off);
    }
    __syncthreads();
    f32x4 acc[8];
    #pragma unroll
    for (int n = 0; n < 8; ++n) acc[n] = (f32x4)(0.f);
    #pragma unroll
    for (int kk = 0; kk < 4; ++kk) {
      const int kb = (kk * 32 + kg) * 2;
      const int rA = wid * 16 + lr;
      s16x8 a = *(const s16x8*)(As + rA * 256 + (kb ^ ((rA & 7) << 4)));
      #pragma unroll
      for (int n = 0; n < 8; ++n) {
        int cc = n * 16 + lr;
        s16x8 b = *(const s16x8*)(Ws + cc * 256 + (kb ^ ((cc & 7) << 4)));
        acc[n] = __builtin_amdgcn_mfma_f32_16x16x32_bf16(a, b, acc[n], 0, 0, 0);
      }
    }
    // epilogue: C layout col=lane&15, row=(lane>>4)*4+j
    const int rbase = mb * 64 + wid * 16 + (lane >> 4) * 4;
    #pragma unroll
    for (int n = 0; n < 8; ++n) {
      int col = n * 16 + lr;
      #pragma unroll
      for (int j = 0; j < 4; ++j) {
        int grow = rbase + j;
        if (grow < N_NODES)
          X[((size_t)rel * N_NODES + grow) * 128 + col] = f2bf(acc[n][j]);
      }
    }
    __syncthreads();   // all waves done with Ws before restage
  }
}

// ---- CSR finalize: per-node counting sort -> rowptr + u32 keys (et*N+src) ----
__global__ void k_bucket_finalize(const unsigned* __restrict__ tmp,
                                  const int* __restrict__ bbase,
                                  int* __restrict__ rowptr,
                                  unsigned* __restrict__ keys) {
  __shared__ int cnt[256];
  __shared__ int off[256];
  const int b = blockIdx.x;
  const int t = threadIdx.x;
  const int s = bbase[b], e = bbase[b + 1];
  cnt[t] = 0;
  __syncthreads();
  for (int i = s + t; i < e; i += 256)
    atomicAdd(&cnt[(tmp[i] >> 19) & 255u], 1);
  __syncthreads();
  int ex = block_scan_excl(cnt[t], t);
  int node = b * 256 + t;
  if (node < N_NODES) rowptr[node] = s + ex;
  off[t] = s + ex;
  __syncthreads();
  for (int i = s + t; i < e; i += 256) {
    unsigned r = tmp[i];
    int pos = atomicAdd(&off[(r >> 19) & 255u], 1);
    keys[pos] = ((r >> 16) & 7u) * N_NODES + (r & 0xffffu);
  }
}

// ---- per-node aggregation: one wave per node, 2 edges per wave-instruction ----
// lane: c2 = lane&31 owns 8B (4 cols), eh = lane>>5 selects edge of pair
template <bool LAST>
__global__ void k_aggregate(const unsigned short* __restrict__ X,
                            const unsigned* __restrict__ keys,
                            const int* __restrict__ rowptr,
                            const float* __restrict__ bias,
                            void* __restrict__ out) {
  const int t = threadIdx.x;
  const int v = blockIdx.x * 4 + (t >> 6);
  const int lane = t & 63;
  const int c2 = lane & 31;            // 8B chunk index within 256B row
  const int eh = lane >> 5;            // which edge of the pair
  const int start = rowptr[v], end = rowptr[v + 1];
  const unsigned char* Xb = (const unsigned char*)X;
  float a0 = 0.f, a1 = 0.f, a2 = 0.f, a3 = 0.f;
  const int cnt = end - start;
  int e = start;
  // 16-pair (32-edge) main loop
  const int n32 = start + (cnt & ~31);
  for (; e < n32; e += 32) {
    unsigned kk[16]; u32x2 pp[16];
    #pragma unroll
    for (int q = 0; q < 16; ++q) kk[q] = keys[e + q * 2 + eh];
    #pragma unroll
    for (int q = 0; q < 16; ++q)
      pp[q] = *(const u32x2*)(Xb + ((size_t)kk[q] << 8) + c2 * 8);
    #pragma unroll
    for (int q = 0; q < 16; ++q) {
      a0 += __uint_as_float(pp[q].x << 16);
      a1 += __uint_as_float(pp[q].x & 0xffff0000u);
      a2 += __uint_as_float(pp[q].y << 16);
      a3 += __uint_as_float(pp[q].y & 0xffff0000u);
    }
  }
  // 2-pair (4-edge) loop
  const int n4 = start + (cnt & ~3);
  for (; e < n4; e += 4) {
    unsigned kk[2]; u32x2 pp[2];
    #pragma unroll
    for (int q = 0; q < 2; ++q) kk[q] = keys[e + q * 2 + eh];
    #pragma unroll
    for (int q = 0; q < 2; ++q)
      pp[q] = *(const u32x2*)(Xb + ((size_t)kk[q] << 8) + c2 * 8);
    #pragma unroll
    for (int q = 0; q < 2; ++q) {
      a0 += __uint_as_float(pp[q].x << 16);
      a1 += __uint_as_float(pp[q].x & 0xffff0000u);
      a2 += __uint_as_float(pp[q].y << 16);
      a3 += __uint_as_float(pp[q].y & 0xffff0000u);
    }
  }
  // 1-pair loop
  const int n2 = start + (cnt & ~1);
  for (; e < n2; e += 2) {
    unsigned k0 = keys[e + eh];
    u32x2 p = *(const u32x2*)(Xb + ((size_t)k0 << 8) + c2 * 8);
    a0 += __uint_as_float(p.x << 16);
    a1 += __uint_as_float(p.x & 0xffff0000u);
    a2 += __uint_as_float(p.y << 16);
    a3 += __uint_as_float(p.y & 0xffff0000u);
  }
  // odd tail + self-loop: eh==0 half only (counted once after merge)
  if (eh == 0) {
    if (e < end) {
      unsigned k0 = keys[e];
      u32x2 p = *(const u32x2*)(Xb + ((size_t)k0 << 8) + c2 * 8);
      a0 += __uint_as_float(p.x << 16);
      a1 += __uint_as_float(p.x & 0xffff0000u);
      a2 += __uint_as_float(p.y << 16);
      a3 += __uint_as_float(p.y & 0xffff0000u);
    }
    { // self-loop pseudo-relation row
      u32x2 p = *(const u32x2*)(Xb + (((size_t)8 * N_NODES + v) << 8) + c2 * 8);
      a0 += __uint_as_float(p.x << 16);
      a1 += __uint_as_float(p.x & 0xffff0000u);
      a2 += __uint_as_float(p.y << 16);
      a3 += __uint_as_float(p.y & 0xffff0000u);
    }
  }
  // merge eh halves: lane L += lane L^32
  a0 += __shfl_xor(a0, 32);
  a1 += __shfl_xor(a1, 32);
  a2 += __shfl_xor(a2, 32);
  a3 += __shfl_xor(a3, 32);
  if (eh == 0) {
    const float4 bb = *(const float4*)(bias + c2 * 4);
    a0 += bb.x; a1 += bb.y; a2 += bb.z; a3 += bb.w;
    if (LAST) {
      f32x4 o; o.x = a0; o.y = a1; o.z = a2; o.w = a3;
      __builtin_nontemporal_store(o, (f32x4*)((float*)out + (size_t)v * 128 + c2 * 4));
    } else {
      u32x2 po;
      po.x = ((unsigned)f2bf(a1) << 16) | (unsigned)f2bf(a0);
      po.y = ((unsigned)f2bf(a3) << 16) | (unsigned)f2bf(a2);
      *(u32x2*)((unsigned short*)out + (size_t)v * 128 + c2 * 4) = po;
    }
  }
}

extern "C" void kernel_launch(void* const* d_in, const int* in_sizes, int n_in,
                              void* d_out, int out_size, void* d_ws, size_t ws_size,
                              hipStream_t stream) {
  const int*   nid  = (const int*)d_in[0];
  const int*   src  = (const int*)d_in[1];
  const int*   dst  = (const int*)d_in[2];
  const int*   et   = (const int*)d_in[3];
  const float* emb  = (const float*)d_in[4];
  const float* W    = (const float*)d_in[5];
  const float* Wl   = (const float*)d_in[6];
  const float* bias = (const float*)d_in[7];

  unsigned char* ws = (unsigned char*)d_ws;
  size_t off = 0;
  auto alloc = [&](size_t bytes) {
    void* p = ws + off;
    off = (off + bytes + 255) & ~(size_t)255;
    return p;
  };
  unsigned short* X    = (unsigned short*)alloc((size_t)9 * N_NODES * HID * 2);  // 115.2 MB
  unsigned short* h0   = (unsigned short*)alloc((size_t)N_NODES * HID * 2);      // 12.8 MB
  unsigned short* h1   = (unsigned short*)alloc((size_t)N_NODES * HID * 2);      // 12.8 MB
  unsigned short* Wt   = (unsigned short*)alloc((size_t)2 * 9 * 128 * 128 * 2);  // 0.6 MB
  unsigned*       keys = (unsigned*)alloc((size_t)N_EDGES * 4);                  // 6.4 MB
  int*            rowp = (int*)alloc((size_t)(N_NODES + 1) * 4);
  int*            histT= (int*)alloc((size_t)TOT * 4);                           // 150 KB
  int*            curL = (int*)alloc((size_t)TOT * 4);                           // 150 KB
  int*            btot = (int*)alloc((size_t)NB * 4);
  int*            bbas = (int*)alloc((size_t)(NB + 1) * 4);
  // scatter tmp aliases h1 (dead until aggregate-L0)
  unsigned*       tmp  = (unsigned*)h1;

  k_pre<<<NGB + NCH + NCW, 256, 0, stream>>>(nid, emb, h0, dst, histT, W, Wl, Wt);
  k_scan_buckets<<<NB, 64, 0, stream>>>(histT, curL, btot);
  k_scan_top<<<1, 256, 0, stream>>>(btot, bbas, rowp);
  // gemm layer 0 (782 blocks) + chunk_scatter (196 blocks) fused
  k_gemm9<true><<<NMB + NCH, 256, 0, stream>>>(h0, Wt, X, src, dst, et, curL, bbas, tmp);
  k_bucket_finalize<<<NB, 256, 0, stream>>>(tmp, bbas, rowp, keys);

  const int agrid = N_NODES / 4;                 // 12500, one wave per node
  k_aggregate<false><<<agrid, 256, 0, stream>>>(X, keys, rowp, bias, (void*)h1);
  k_gemm9<false><<<NMB, 256, 0, stream>>>(h1, Wt + (size_t)9 * 128 * 128, X,
                                          src, dst, et, curL, bbas, tmp);
  k_aggregate<true><<<agrid, 256, 0, stream>>>(X, keys, rowp, bias + HID, (void*)d_out);
}

// Round 14
// 263.656 us; speedup vs baseline: 1.0869x; 1.0869x over previous
//
#include <hip/hip_runtime.h>
#include <stdint.h>

#define N_NODES 50000
#define N_EDGES 1600000
#define HID 128
#define NB 196      // dst buckets of 256 nodes
#define CHUNK 8192
#define NCH 196     // ceil(1600000 / 8192)
#define TOT (NB * NCH)
#define NGB 6250    // gather_h0 blocks (N*32/256)
#define NCW 1152    // convert_w blocks
#define NMB 782     // gemm 64-row tiles

typedef float f32x4 __attribute__((ext_vector_type(4)));
typedef float f32x2 __attribute__((ext_vector_type(2)));
typedef short s16x8 __attribute__((ext_vector_type(8)));
typedef unsigned u32x4 __attribute__((ext_vector_type(4)));

__device__ __forceinline__ unsigned short f2bf(float f) {
  unsigned u = __float_as_uint(f);
  u += 0x7fffu + ((u >> 16) & 1u);   // RNE
  return (unsigned short)(u >> 16);
}

__device__ __forceinline__ int block_scan_excl(int v, int t) {
  const int lane = t & 63, wid = t >> 6;
  int incl = v;
  #pragma unroll
  for (int o = 1; o < 64; o <<= 1) {
    int nv = __shfl_up(incl, o);
    if (lane >= o) incl += nv;
  }
  __shared__ int wsum[4];
  if (lane == 63) wsum[wid] = incl;
  __syncthreads();
  int wbase = 0;
  #pragma unroll
  for (int w = 0; w < 3; ++w) if (w < wid) wbase += wsum[w];
  return wbase + incl - v;
}

// ---- pre-kernel: gather_h0 | chunk_hist | convert_w ----
__global__ void k_pre(const int* __restrict__ nid, const float* __restrict__ emb,
                      unsigned short* __restrict__ h0,
                      const int* __restrict__ dst, int* __restrict__ histT,
                      const float* __restrict__ W, const float* __restrict__ Wl,
                      unsigned short* __restrict__ Wt) {
  const int bid = blockIdx.x, t = threadIdx.x;
  if (bid < NGB) {                       // h0 = bf16(emb[node_id])
    int g = bid * 256 + t;
    int i = g >> 5, c = (g & 31) * 4;
    const float4 v = *(const float4*)(emb + (size_t)nid[i] * HID + c);
    ushort4 o;
    o.x = f2bf(v.x); o.y = f2bf(v.y); o.z = f2bf(v.z); o.w = f2bf(v.w);
    *(ushort4*)(h0 + (size_t)i * HID + c) = o;
  } else if (bid < NGB + NCH) {          // per-chunk bucket histogram
    __shared__ int h[NB];
    const int c = bid - NGB;
    if (t < NB) h[t] = 0;
    __syncthreads();
    int base = c * CHUNK;
    #pragma unroll 4
    for (int i = t; i < CHUNK; i += 256) {
      int e = base + i;
      if (e < N_EDGES) atomicAdd(&h[dst[e] >> 8], 1);
    }
    __syncthreads();
    if (t < NB) histT[t * NCH + c] = h[t];
  } else {                               // Wt[l][r][k][d] = W[l][r][d][k]
    int idx = (bid - NGB - NCH) * 256 + t;
    int d  = idx & 127;
    int k  = (idx >> 7) & 127;
    int lr = idx >> 14;
    int l = lr / 9, r = lr - l * 9;
    float v;
    if (r < 8) v = W[((((size_t)l * 8 + r) * 128) + d) * 128 + k];
    else       v = Wl[(((size_t)l * 128) + d) * 128 + k];
    Wt[idx] = f2bf(v);
  }
}

// ---- CSR pass B1: per-bucket chunk-prefix scan (196 blocks, 1 wave each) ----
__global__ void k_scan_buckets(const int* __restrict__ histT, int* __restrict__ curL,
                               int* __restrict__ btot) {
  const int b = blockIdx.x, tid = threadIdx.x;   // 64 threads
  int carry = 0;
  #pragma unroll
  for (int k = 0; k < 4; ++k) {
    int c = k * 64 + tid;
    int v = (c < NCH) ? histT[b * NCH + c] : 0;
    int incl = v;
    #pragma unroll
    for (int o = 1; o < 64; o <<= 1) {
      int nv = __shfl_up(incl, o);
      if (tid >= o) incl += nv;
    }
    if (c < NCH) curL[b * NCH + c] = carry + incl - v;
    carry += __shfl(incl, 63);
  }
  if (tid == 0) btot[b] = carry;
}

// ---- CSR pass B2: scan 196 bucket totals -> bbase ----
__global__ void k_scan_top(const int* __restrict__ btot, int* __restrict__ bbase,
                           int* __restrict__ rowptr) {
  const int t = threadIdx.x;
  int v = (t < NB) ? btot[t] : 0;
  int ex = block_scan_excl(v, t);
  if (t < NB) bbase[t] = ex;
  if (t == 0) { bbase[NB] = N_EDGES; rowptr[N_NODES] = N_EDGES; }
}

// ---- GEMM (A fragments from global/L2, only W in LDS, 5 blocks/CU) ----
// X[rel][n][k] = sum_d A[n][d] * Wt[rel][k][d]
template <bool SCAT>
__global__ __launch_bounds__(256, 5) void k_gemm9(
    const unsigned short* __restrict__ A,   // [N][128] bf16
    const unsigned short* __restrict__ Bw,  // [9][128][128] bf16 (this layer)
    unsigned short* __restrict__ X,         // [9][N][128] bf16
    const int* __restrict__ src, const int* __restrict__ dst,
    const int* __restrict__ et, const int* __restrict__ curL,
    const int* __restrict__ bbase, unsigned* __restrict__ tmp) {
  __shared__ unsigned char Ws[32768];   // 128 rows x 256B (swizzled)
  const int t = threadIdx.x;
  if (SCAT && blockIdx.x >= NMB) {      // chunk-local scatter role
    int* off2 = (int*)Ws;               // overlay LDS
    const int c = blockIdx.x - NMB;
    if (t < NB) off2[t] = curL[t * NCH + c] + bbase[t];
    __syncthreads();
    int base = c * CHUNK;
    #pragma unroll 4
    for (int i = t; i < CHUNK; i += 256) {
      int e = base + i;
      if (e < N_EDGES) {
        int d = dst[e];
        int pos = atomicAdd(&off2[d >> 8], 1);
        tmp[pos] = ((unsigned)(d & 255) << 19) | ((unsigned)et[e] << 16) | (unsigned)src[e];
      }
    }
    return;
  }
  const int mb = blockIdx.x;
  const int wid = t >> 6, lane = t & 63;
  const int lr = lane & 15, kg = (lane >> 4) * 8;
  const int rAg = mb * 64 + wid * 16 + lr;     // A row this lane reads
  const bool rok = rAg < N_NODES;
  const unsigned short* Arow = A + (size_t)(rok ? rAg : 0) * 128;
  for (int rel = 0; rel < 9; ++rel) {
    // stage W_rel (32KB), swizzled
    const unsigned char* Bsrc = (const unsigned char*)(Bw + (size_t)rel * 16384);
    #pragma unroll
    for (int c = 0; c < 8; ++c) {
      int off = c * 4096 + t * 16;
      int row = off >> 8, ib = off & 255;
      *(u32x4*)(Ws + row * 256 + (ib ^ ((row & 7) << 4))) = *(const u32x4*)(Bsrc + off);
    }
    __syncthreads();
    f32x4 acc[8];
    #pragma unroll
    for (int n = 0; n < 8; ++n) acc[n] = (f32x4)(0.f);
    #pragma unroll
    for (int kk = 0; kk < 4; ++kk) {
      const int ke = kk * 32 + kg;           // element offset in row
      s16x8 a = (s16x8)(short)0;
      if (rok) a = *(const s16x8*)(Arow + ke);
      const int kb = ke * 2;
      #pragma unroll
      for (int n = 0; n < 8; ++n) {
        int cc = n * 16 + lr;
        s16x8 b = *(const s16x8*)(Ws + cc * 256 + (kb ^ ((cc & 7) << 4)));
        acc[n] = __builtin_amdgcn_mfma_f32_16x16x32_bf16(a, b, acc[n], 0, 0, 0);
      }
    }
    // epilogue: C layout col=lane&15, row=(lane>>4)*4+j
    const int rbase = mb * 64 + wid * 16 + (lane >> 4) * 4;
    #pragma unroll
    for (int n = 0; n < 8; ++n) {
      int col = n * 16 + lr;
      #pragma unroll
      for (int j = 0; j < 4; ++j) {
        int grow = rbase + j;
        if (grow < N_NODES)
          X[((size_t)rel * N_NODES + grow) * 128 + col] = f2bf(acc[n][j]);
      }
    }
    __syncthreads();   // all waves done with Ws before restage
  }
}

// ---- CSR finalize: per-node counting sort -> rowptr + u32 keys (et*N+src) ----
__global__ void k_bucket_finalize(const unsigned* __restrict__ tmp,
                                  const int* __restrict__ bbase,
                                  int* __restrict__ rowptr,
                                  unsigned* __restrict__ keys) {
  __shared__ int cnt[256];
  __shared__ int off[256];
  const int b = blockIdx.x;
  const int t = threadIdx.x;
  const int s = bbase[b], e = bbase[b + 1];
  cnt[t] = 0;
  __syncthreads();
  for (int i = s + t; i < e; i += 256)
    atomicAdd(&cnt[(tmp[i] >> 19) & 255u], 1);
  __syncthreads();
  int ex = block_scan_excl(cnt[t], t);
  int node = b * 256 + t;
  if (node < N_NODES) rowptr[node] = s + ex;
  off[t] = s + ex;
  __syncthreads();
  for (int i = s + t; i < e; i += 256) {
    unsigned r = tmp[i];
    int pos = atomicAdd(&off[(r >> 19) & 255u], 1);
    keys[pos] = ((r >> 16) & 7u) * N_NODES + (r & 0xffffu);
  }
}

// ---- per-node aggregation over CSR: one wave per node, 16-deep unroll ----
template <bool LAST>
__global__ void k_aggregate(const unsigned short* __restrict__ X,
                            const unsigned* __restrict__ keys,
                            const int* __restrict__ rowptr,
                            const float* __restrict__ bias,
                            void* __restrict__ out) {
  const int t = threadIdx.x;
  const int v = blockIdx.x * 4 + (t >> 6);
  const int lane = t & 63;
  const int start = rowptr[v], end = rowptr[v + 1];
  const unsigned char* Xb = (const unsigned char*)X;
  float a0 = 0.f, a1 = 0.f;
  int e = start;
  const int n16 = start + ((end - start) & ~15);
  for (; e < n16; e += 16) {
    unsigned kk[16], pp[16];
    #pragma unroll
    for (int q = 0; q < 16; ++q) kk[q] = keys[e + q];
    #pragma unroll
    for (int q = 0; q < 16; ++q)
      pp[q] = *(const unsigned*)(Xb + ((size_t)kk[q] << 8) + lane * 4);
    #pragma unroll
    for (int q = 0; q < 16; ++q) {
      a0 += __uint_as_float(pp[q] << 16);
      a1 += __uint_as_float(pp[q] & 0xffff0000u);
    }
  }
  const int n4 = start + ((end - start) & ~3);
  for (; e < n4; e += 4) {
    unsigned kk[4], pp[4];
    #pragma unroll
    for (int q = 0; q < 4; ++q) kk[q] = keys[e + q];
    #pragma unroll
    for (int q = 0; q < 4; ++q)
      pp[q] = *(const unsigned*)(Xb + ((size_t)kk[q] << 8) + lane * 4);
    #pragma unroll
    for (int q = 0; q < 4; ++q) {
      a0 += __uint_as_float(pp[q] << 16);
      a1 += __uint_as_float(pp[q] & 0xffff0000u);
    }
  }
  for (; e < end; ++e) {
    unsigned k0 = keys[e];
    unsigned p0 = *(const unsigned*)(Xb + ((size_t)k0 << 8) + lane * 4);
    a0 += __uint_as_float(p0 << 16); a1 += __uint_as_float(p0 & 0xffff0000u);
  }
  { // self-loop pseudo-relation row
    unsigned p = *(const unsigned*)(Xb + (((size_t)8 * N_NODES + v) << 8) + lane * 4);
    a0 += __uint_as_float(p << 16); a1 += __uint_as_float(p & 0xffff0000u);
  }
  const float2 bb = *(const float2*)(bias + lane * 2);
  a0 += bb.x; a1 += bb.y;
  if (LAST) {
    f32x2 o; o.x = a0; o.y = a1;
    __builtin_nontemporal_store(o, (f32x2*)((float*)out + (size_t)v * 128 + lane * 2));
  } else {
    unsigned po = ((unsigned)f2bf(a1) << 16) | (unsigned)f2bf(a0);
    *(unsigned*)((unsigned short*)out + (size_t)v * 128 + lane * 2) = po;
  }
}

extern "C" void kernel_launch(void* const* d_in, const int* in_sizes, int n_in,
                              void* d_out, int out_size, void* d_ws, size_t ws_size,
                              hipStream_t stream) {
  const int*   nid  = (const int*)d_in[0];
  const int*   src  = (const int*)d_in[1];
  const int*   dst  = (const int*)d_in[2];
  const int*   et   = (const int*)d_in[3];
  const float* emb  = (const float*)d_in[4];
  const float* W    = (const float*)d_in[5];
  const float* Wl   = (const float*)d_in[6];
  const float* bias = (const float*)d_in[7];

  unsigned char* ws = (unsigned char*)d_ws;
  size_t off = 0;
  auto alloc = [&](size_t bytes) {
    void* p = ws + off;
    off = (off + bytes + 255) & ~(size_t)255;
    return p;
  };
  unsigned short* X    = (unsigned short*)alloc((size_t)9 * N_NODES * HID * 2);  // 115.2 MB
  unsigned short* h0   = (unsigned short*)alloc((size_t)N_NODES * HID * 2);      // 12.8 MB
  unsigned short* h1   = (unsigned short*)alloc((size_t)N_NODES * HID * 2);      // 12.8 MB
  unsigned short* Wt   = (unsigned short*)alloc((size_t)2 * 9 * 128 * 128 * 2);  // 0.6 MB
  unsigned*       keys = (unsigned*)alloc((size_t)N_EDGES * 4);                  // 6.4 MB
  int*            rowp = (int*)alloc((size_t)(N_NODES + 1) * 4);
  int*            histT= (int*)alloc((size_t)TOT * 4);                           // 150 KB
  int*            curL = (int*)alloc((size_t)TOT * 4);                           // 150 KB
  int*            btot = (int*)alloc((size_t)NB * 4);
  int*            bbas = (int*)alloc((size_t)(NB + 1) * 4);
  // scatter tmp aliases h1 (dead until aggregate-L0)
  unsigned*       tmp  = (unsigned*)h1;

  k_pre<<<NGB + NCH + NCW, 256, 0, stream>>>(nid, emb, h0, dst, histT, W, Wl, Wt);
  k_scan_buckets<<<NB, 64, 0, stream>>>(histT, curL, btot);
  k_scan_top<<<1, 256, 0, stream>>>(btot, bbas, rowp);
  // gemm layer 0 (782 blocks) + chunk_scatter (196 blocks) fused
  k_gemm9<true><<<NMB + NCH, 256, 0, stream>>>(h0, Wt, X, src, dst, et, curL, bbas, tmp);
  k_bucket_finalize<<<NB, 256, 0, stream>>>(tmp, bbas, rowp, keys);

  const int agrid = N_NODES / 4;                 // 12500, one wave per node
  k_aggregate<false><<<agrid, 256, 0, stream>>>(X, keys, rowp, bias, (void*)h1);
  k_gemm9<false><<<NMB, 256, 0, stream>>>(h1, Wt + (size_t)9 * 128 * 128, X,
                                          src, dst, et, curL, bbas, tmp);
  k_aggregate<true><<<agrid, 256, 0, stream>>>(X, keys, rowp, bias + HID, (void*)d_out);
}

// Round 15
// 245.360 us; speedup vs baseline: 1.1679x; 1.0746x over previous
//
#include <hip/hip_runtime.h>
#include <stdint.h>

#define N_NODES 50000
#define N_EDGES 1600000
#define HID 128
#define NB 196      // dst buckets of 256 nodes
#define CHUNK 8192
#define NCH 196     // ceil(1600000 / 8192)
#define TOT (NB * NCH)
#define NGB 6250    // gather_h0 blocks (N*32/256)
#define NCW 1152    // convert_w blocks
#define NMB 782     // gemm 64-row tiles

typedef float f32x4 __attribute__((ext_vector_type(4)));
typedef float f32x2 __attribute__((ext_vector_type(2)));
typedef short s16x8 __attribute__((ext_vector_type(8)));
typedef unsigned u32x4 __attribute__((ext_vector_type(4)));

__device__ __forceinline__ unsigned short f2bf(float f) {
  unsigned u = __float_as_uint(f);
  u += 0x7fffu + ((u >> 16) & 1u);   // RNE
  return (unsigned short)(u >> 16);
}

__device__ __forceinline__ int block_scan_excl(int v, int t) {
  const int lane = t & 63, wid = t >> 6;
  int incl = v;
  #pragma unroll
  for (int o = 1; o < 64; o <<= 1) {
    int nv = __shfl_up(incl, o);
    if (lane >= o) incl += nv;
  }
  __shared__ int wsum[4];
  if (lane == 63) wsum[wid] = incl;
  __syncthreads();
  int wbase = 0;
  #pragma unroll
  for (int w = 0; w < 3; ++w) if (w < wid) wbase += wsum[w];
  return wbase + incl - v;
}

// ---- pre-kernel: gather_h0 | chunk_hist | convert_w ----
__global__ void k_pre(const int* __restrict__ nid, const float* __restrict__ emb,
                      unsigned short* __restrict__ h0,
                      const int* __restrict__ dst, int* __restrict__ histT,
                      const float* __restrict__ W, const float* __restrict__ Wl,
                      unsigned short* __restrict__ Wt) {
  const int bid = blockIdx.x, t = threadIdx.x;
  if (bid < NGB) {                       // h0 = bf16(emb[node_id])
    int g = bid * 256 + t;
    int i = g >> 5, c = (g & 31) * 4;
    const float4 v = *(const float4*)(emb + (size_t)nid[i] * HID + c);
    ushort4 o;
    o.x = f2bf(v.x); o.y = f2bf(v.y); o.z = f2bf(v.z); o.w = f2bf(v.w);
    *(ushort4*)(h0 + (size_t)i * HID + c) = o;
  } else if (bid < NGB + NCH) {          // per-chunk bucket histogram
    __shared__ int h[NB];
    const int c = bid - NGB;
    if (t < NB) h[t] = 0;
    __syncthreads();
    int base = c * CHUNK;
    #pragma unroll 4
    for (int i = t; i < CHUNK; i += 256) {
      int e = base + i;
      if (e < N_EDGES) atomicAdd(&h[dst[e] >> 8], 1);
    }
    __syncthreads();
    if (t < NB) histT[t * NCH + c] = h[t];
  } else {                               // Wt[l][r][k][d] = W[l][r][d][k]
    int idx = (bid - NGB - NCH) * 256 + t;
    int d  = idx & 127;
    int k  = (idx >> 7) & 127;
    int lr = idx >> 14;
    int l = lr / 9, r = lr - l * 9;
    float v;
    if (r < 8) v = W[((((size_t)l * 8 + r) * 128) + d) * 128 + k];
    else       v = Wl[(((size_t)l * 128) + d) * 128 + k];
    Wt[idx] = f2bf(v);
  }
}

// ---- CSR pass B1: per-bucket chunk-prefix scan (196 blocks, 1 wave each) ----
__global__ void k_scan_buckets(const int* __restrict__ histT, int* __restrict__ curL,
                               int* __restrict__ btot) {
  const int b = blockIdx.x, tid = threadIdx.x;   // 64 threads
  int carry = 0;
  #pragma unroll
  for (int k = 0; k < 4; ++k) {
    int c = k * 64 + tid;
    int v = (c < NCH) ? histT[b * NCH + c] : 0;
    int incl = v;
    #pragma unroll
    for (int o = 1; o < 64; o <<= 1) {
      int nv = __shfl_up(incl, o);
      if (tid >= o) incl += nv;
    }
    if (c < NCH) curL[b * NCH + c] = carry + incl - v;
    carry += __shfl(incl, 63);
  }
  if (tid == 0) btot[b] = carry;
}

// ---- CSR pass B2: scan 196 bucket totals -> bbase ----
__global__ void k_scan_top(const int* __restrict__ btot, int* __restrict__ bbase,
                           int* __restrict__ rowptr) {
  const int t = threadIdx.x;
  int v = (t < NB) ? btot[t] : 0;
  int ex = block_scan_excl(v, t);
  if (t < NB) bbase[t] = ex;
  if (t == 0) { bbase[NB] = N_EDGES; rowptr[N_NODES] = N_EDGES; }
}

// ---- GEMM: A in registers (rel-invariant), W in LDS, 5 blocks/CU ----
// X[rel][n][k] = sum_d A[n][d] * Wt[rel][k][d]
template <bool SCAT>
__global__ __launch_bounds__(256, 5) void k_gemm9(
    const unsigned short* __restrict__ A,   // [N][128] bf16
    const unsigned short* __restrict__ Bw,  // [9][128][128] bf16 (this layer)
    unsigned short* __restrict__ X,         // [9][N][128] bf16
    const int* __restrict__ src, const int* __restrict__ dst,
    const int* __restrict__ et, const int* __restrict__ curL,
    const int* __restrict__ bbase, unsigned* __restrict__ tmp) {
  __shared__ unsigned char Ws[32768];   // 128 rows x 256B (swizzled)
  const int t = threadIdx.x;
  if (SCAT && blockIdx.x >= NMB) {      // chunk-local scatter role
    int* off2 = (int*)Ws;               // overlay LDS
    const int c = blockIdx.x - NMB;
    if (t < NB) off2[t] = curL[t * NCH + c] + bbase[t];
    __syncthreads();
    int base = c * CHUNK;
    #pragma unroll 4
    for (int i = t; i < CHUNK; i += 256) {
      int e = base + i;
      if (e < N_EDGES) {
        int d = dst[e];
        int pos = atomicAdd(&off2[d >> 8], 1);
        tmp[pos] = ((unsigned)(d & 255) << 19) | ((unsigned)et[e] << 16) | (unsigned)src[e];
      }
    }
    return;
  }
  const int mb = blockIdx.x;
  const int wid = t >> 6, lane = t & 63;
  const int lr = lane & 15, kg = (lane >> 4) * 8;
  const int rAg = mb * 64 + wid * 16 + lr;     // A row this lane reads
  const bool rok = rAg < N_NODES;
  const unsigned short* Arow = A + (size_t)(rok ? rAg : 0) * 128;
  // hoist A fragments into registers ONCE (rel-invariant): 16 VGPRs
  s16x8 a[4];
  #pragma unroll
  for (int kk = 0; kk < 4; ++kk) {
    s16x8 v = (s16x8)(short)0;
    if (rok) v = *(const s16x8*)(Arow + kk * 32 + kg);
    a[kk] = v;
  }
  for (int rel = 0; rel < 9; ++rel) {
    // stage W_rel (32KB), swizzled
    const unsigned char* Bsrc = (const unsigned char*)(Bw + (size_t)rel * 16384);
    #pragma unroll
    for (int c = 0; c < 8; ++c) {
      int off = c * 4096 + t * 16;
      int row = off >> 8, ib = off & 255;
      *(u32x4*)(Ws + row * 256 + (ib ^ ((row & 7) << 4))) = *(const u32x4*)(Bsrc + off);
    }
    __syncthreads();
    f32x4 acc[8];
    #pragma unroll
    for (int n = 0; n < 8; ++n) acc[n] = (f32x4)(0.f);
    #pragma unroll
    for (int kk = 0; kk < 4; ++kk) {
      const int kb = (kk * 32 + kg) * 2;
      #pragma unroll
      for (int n = 0; n < 8; ++n) {
        int cc = n * 16 + lr;
        s16x8 b = *(const s16x8*)(Ws + cc * 256 + (kb ^ ((cc & 7) << 4)));
        acc[n] = __builtin_amdgcn_mfma_f32_16x16x32_bf16(a[kk], b, acc[n], 0, 0, 0);
      }
    }
    // epilogue: C layout col=lane&15, row=(lane>>4)*4+j
    const int rbase = mb * 64 + wid * 16 + (lane >> 4) * 4;
    #pragma unroll
    for (int n = 0; n < 8; ++n) {
      int col = n * 16 + lr;
      #pragma unroll
      for (int j = 0; j < 4; ++j) {
        int grow = rbase + j;
        if (grow < N_NODES)
          X[((size_t)rel * N_NODES + grow) * 128 + col] = f2bf(acc[n][j]);
      }
    }
    __syncthreads();   // all waves done with Ws before restage
  }
}

// ---- CSR finalize: per-node counting sort -> rowptr + u32 keys (et*N+src) ----
__global__ void k_bucket_finalize(const unsigned* __restrict__ tmp,
                                  const int* __restrict__ bbase,
                                  int* __restrict__ rowptr,
                                  unsigned* __restrict__ keys) {
  __shared__ int cnt[256];
  __shared__ int off[256];
  const int b = blockIdx.x;
  const int t = threadIdx.x;
  const int s = bbase[b], e = bbase[b + 1];
  cnt[t] = 0;
  __syncthreads();
  for (int i = s + t; i < e; i += 256)
    atomicAdd(&cnt[(tmp[i] >> 19) & 255u], 1);
  __syncthreads();
  int ex = block_scan_excl(cnt[t], t);
  int node = b * 256 + t;
  if (node < N_NODES) rowptr[node] = s + ex;
  off[t] = s + ex;
  __syncthreads();
  for (int i = s + t; i < e; i += 256) {
    unsigned r = tmp[i];
    int pos = atomicAdd(&off[(r >> 19) & 255u], 1);
    keys[pos] = ((r >> 16) & 7u) * N_NODES + (r & 0xffffu);
  }
}

// ---- per-node aggregation over CSR: one wave per node, 16-deep unroll ----
template <bool LAST>
__global__ void k_aggregate(const unsigned short* __restrict__ X,
                            const unsigned* __restrict__ keys,
                            const int* __restrict__ rowptr,
                            const float* __restrict__ bias,
                            void* __restrict__ out) {
  const int t = threadIdx.x;
  const int v = blockIdx.x * 4 + (t >> 6);
  const int lane = t & 63;
  const int start = rowptr[v], end = rowptr[v + 1];
  const unsigned char* Xb = (const unsigned char*)X;
  float a0 = 0.f, a1 = 0.f;
  int e = start;
  const int n16 = start + ((end - start) & ~15);
  for (; e < n16; e += 16) {
    unsigned kk[16], pp[16];
    #pragma unroll
    for (int q = 0; q < 16; ++q) kk[q] = keys[e + q];
    #pragma unroll
    for (int q = 0; q < 16; ++q)
      pp[q] = *(const unsigned*)(Xb + ((size_t)kk[q] << 8) + lane * 4);
    #pragma unroll
    for (int q = 0; q < 16; ++q) {
      a0 += __uint_as_float(pp[q] << 16);
      a1 += __uint_as_float(pp[q] & 0xffff0000u);
    }
  }
  const int n4 = start + ((end - start) & ~3);
  for (; e < n4; e += 4) {
    unsigned kk[4], pp[4];
    #pragma unroll
    for (int q = 0; q < 4; ++q) kk[q] = keys[e + q];
    #pragma unroll
    for (int q = 0; q < 4; ++q)
      pp[q] = *(const unsigned*)(Xb + ((size_t)kk[q] << 8) + lane * 4);
    #pragma unroll
    for (int q = 0; q < 4; ++q) {
      a0 += __uint_as_float(pp[q] << 16);
      a1 += __uint_as_float(pp[q] & 0xffff0000u);
    }
  }
  for (; e < end; ++e) {
    unsigned k0 = keys[e];
    unsigned p0 = *(const unsigned*)(Xb + ((size_t)k0 << 8) + lane * 4);
    a0 += __uint_as_float(p0 << 16); a1 += __uint_as_float(p0 & 0xffff0000u);
  }
  { // self-loop pseudo-relation row
    unsigned p = *(const unsigned*)(Xb + (((size_t)8 * N_NODES + v) << 8) + lane * 4);
    a0 += __uint_as_float(p << 16); a1 += __uint_as_float(p & 0xffff0000u);
  }
  const float2 bb = *(const float2*)(bias + lane * 2);
  a0 += bb.x; a1 += bb.y;
  if (LAST) {
    f32x2 o; o.x = a0; o.y = a1;
    __builtin_nontemporal_store(o, (f32x2*)((float*)out + (size_t)v * 128 + lane * 2));
  } else {
    unsigned po = ((unsigned)f2bf(a1) << 16) | (unsigned)f2bf(a0);
    *(unsigned*)((unsigned short*)out + (size_t)v * 128 + lane * 2) = po;
  }
}

extern "C" void kernel_launch(void* const* d_in, const int* in_sizes, int n_in,
                              void* d_out, int out_size, void* d_ws, size_t ws_size,
                              hipStream_t stream) {
  const int*   nid  = (const int*)d_in[0];
  const int*   src  = (const int*)d_in[1];
  const int*   dst  = (const int*)d_in[2];
  const int*   et   = (const int*)d_in[3];
  const float* emb  = (const float*)d_in[4];
  const float* W    = (const float*)d_in[5];
  const float* Wl   = (const float*)d_in[6];
  const float* bias = (const float*)d_in[7];

  unsigned char* ws = (unsigned char*)d_ws;
  size_t off = 0;
  auto alloc = [&](size_t bytes) {
    void* p = ws + off;
    off = (off + bytes + 255) & ~(size_t)255;
    return p;
  };
  unsigned short* X    = (unsigned short*)alloc((size_t)9 * N_NODES * HID * 2);  // 115.2 MB
  unsigned short* h0   = (unsigned short*)alloc((size_t)N_NODES * HID * 2);      // 12.8 MB
  unsigned short* h1   = (unsigned short*)alloc((size_t)N_NODES * HID * 2);      // 12.8 MB
  unsigned short* Wt   = (unsigned short*)alloc((size_t)2 * 9 * 128 * 128 * 2);  // 0.6 MB
  unsigned*       keys = (unsigned*)alloc((size_t)N_EDGES * 4);                  // 6.4 MB
  int*            rowp = (int*)alloc((size_t)(N_NODES + 1) * 4);
  int*            histT= (int*)alloc((size_t)TOT * 4);                           // 150 KB
  int*            curL = (int*)alloc((size_t)TOT * 4);                           // 150 KB
  int*            btot = (int*)alloc((size_t)NB * 4);
  int*            bbas = (int*)alloc((size_t)(NB + 1) * 4);
  // scatter tmp aliases h1 (dead until aggregate-L0)
  unsigned*       tmp  = (unsigned*)h1;

  k_pre<<<NGB + NCH + NCW, 256, 0, stream>>>(nid, emb, h0, dst, histT, W, Wl, Wt);
  k_scan_buckets<<<NB, 64, 0, stream>>>(histT, curL, btot);
  k_scan_top<<<1, 256, 0, stream>>>(btot, bbas, rowp);
  // gemm layer 0 (782 blocks) + chunk_scatter (196 blocks) fused
  k_gemm9<true><<<NMB + NCH, 256, 0, stream>>>(h0, Wt, X, src, dst, et, curL, bbas, tmp);
  k_bucket_finalize<<<NB, 256, 0, stream>>>(tmp, bbas, rowp, keys);

  const int agrid = N_NODES / 4;                 // 12500, one wave per node
  k_aggregate<false><<<agrid, 256, 0, stream>>>(X, keys, rowp, bias, (void*)h1);
  k_gemm9<false><<<NMB, 256, 0, stream>>>(h1, Wt + (size_t)9 * 128 * 128, X,
                                          src, dst, et, curL, bbas, tmp);
  k_aggregate<true><<<agrid, 256, 0, stream>>>(X, keys, rowp, bias + HID, (void*)d_out);
}

// Round 16
// 243.527 us; speedup vs baseline: 1.1767x; 1.0075x over previous
//
#include <hip/hip_runtime.h>
#include <stdint.h>

#define N_NODES 50000
#define N_EDGES 1600000
#define HID 128
#define NB 196      // dst buckets of 256 nodes
#define CHUNK 8192
#define NCH 196     // ceil(1600000 / 8192)
#define TOT (NB * NCH)
#define NGB 6250    // gather_h0 blocks (N*32/256)
#define NCW 1152    // convert_w blocks
#define NMB 782     // gemm 64-row tiles

typedef float f32x4 __attribute__((ext_vector_type(4)));
typedef float f32x2 __attribute__((ext_vector_type(2)));
typedef short s16x8 __attribute__((ext_vector_type(8)));
typedef unsigned u32x4 __attribute__((ext_vector_type(4)));

// permuted X/h column layout: natural col c lives at position p
//   p(c) = (c&15)*8 + (c>>4)      c(p) = (p&7)*16 + (p>>3)
__device__ __forceinline__ int pos2col(int p) { return (p & 7) * 16 + (p >> 3); }

__device__ __forceinline__ unsigned short f2bf(float f) {
  unsigned u = __float_as_uint(f);
  u += 0x7fffu + ((u >> 16) & 1u);   // RNE
  return (unsigned short)(u >> 16);
}

__device__ __forceinline__ int block_scan_excl(int v, int t) {
  const int lane = t & 63, wid = t >> 6;
  int incl = v;
  #pragma unroll
  for (int o = 1; o < 64; o <<= 1) {
    int nv = __shfl_up(incl, o);
    if (lane >= o) incl += nv;
  }
  __shared__ int wsum[4];
  if (lane == 63) wsum[wid] = incl;
  __syncthreads();
  int wbase = 0;
  #pragma unroll
  for (int w = 0; w < 3; ++w) if (w < wid) wbase += wsum[w];
  return wbase + incl - v;
}

// ---- pre-kernel: gather_h0(perm) | chunk_hist | convert_w(perm-d) | biasP ----
__global__ void k_pre(const int* __restrict__ nid, const float* __restrict__ emb,
                      unsigned short* __restrict__ h0,
                      const int* __restrict__ dst, int* __restrict__ histT,
                      const float* __restrict__ W, const float* __restrict__ Wl,
                      unsigned short* __restrict__ Wt,
                      const float* __restrict__ bias, float* __restrict__ biasP) {
  const int bid = blockIdx.x, t = threadIdx.x;
  if (bid < NGB) {                       // h0[i][p] = bf16(emb[nid[i]][c(p)])
    int g = bid * 256 + t;
    int i = g >> 5, s = g & 31;          // s handles positions 4s..4s+3
    const float* erow = emb + (size_t)nid[i] * HID;
    ushort4 o;
    o.x = f2bf(erow[pos2col(4 * s + 0)]);
    o.y = f2bf(erow[pos2col(4 * s + 1)]);
    o.z = f2bf(erow[pos2col(4 * s + 2)]);
    o.w = f2bf(erow[pos2col(4 * s + 3)]);
    *(ushort4*)(h0 + (size_t)i * HID + 4 * s) = o;
  } else if (bid < NGB + NCH) {          // per-chunk bucket histogram
    __shared__ int h[NB];
    const int c = bid - NGB;
    if (t < NB) h[t] = 0;
    __syncthreads();
    int base = c * CHUNK;
    #pragma unroll 4
    for (int i = t; i < CHUNK; i += 256) {
      int e = base + i;
      if (e < N_EDGES) atomicAdd(&h[dst[e] >> 8], 1);
    }
    __syncthreads();
    if (t < NB) histT[t * NCH + c] = h[t];
  } else if (bid < NGB + NCH + NCW) {    // Wt[l][r][k][p] = W[l][r][c(p)][k]
    int idx = (bid - NGB - NCH) * 256 + t;
    int p  = idx & 127;
    int k  = (idx >> 7) & 127;
    int lr = idx >> 14;
    int l = lr / 9, r = lr - l * 9;
    int d = pos2col(p);
    float v;
    if (r < 8) v = W[((((size_t)l * 8 + r) * 128) + d) * 128 + k];
    else       v = Wl[(((size_t)l * 128) + d) * 128 + k];
    Wt[idx] = f2bf(v);
  } else {                               // biasP[l][p] = bias[l][c(p)]
    int l = t >> 7, p = t & 127;
    biasP[t] = bias[l * 128 + pos2col(p)];
  }
}

// ---- CSR pass B1: per-bucket chunk-prefix scan (196 blocks, 1 wave each) ----
__global__ void k_scan_buckets(const int* __restrict__ histT, int* __restrict__ curL,
                               int* __restrict__ btot) {
  const int b = blockIdx.x, tid = threadIdx.x;   // 64 threads
  int carry = 0;
  #pragma unroll
  for (int k = 0; k < 4; ++k) {
    int c = k * 64 + tid;
    int v = (c < NCH) ? histT[b * NCH + c] : 0;
    int incl = v;
    #pragma unroll
    for (int o = 1; o < 64; o <<= 1) {
      int nv = __shfl_up(incl, o);
      if (tid >= o) incl += nv;
    }
    if (c < NCH) curL[b * NCH + c] = carry + incl - v;
    carry += __shfl(incl, 63);
  }
  if (tid == 0) btot[b] = carry;
}

// ---- CSR pass B2: scan 196 bucket totals -> bbase ----
__global__ void k_scan_top(const int* __restrict__ btot, int* __restrict__ bbase,
                           int* __restrict__ rowptr) {
  const int t = threadIdx.x;
  int v = (t < NB) ? btot[t] : 0;
  int ex = block_scan_excl(v, t);
  if (t < NB) bbase[t] = ex;
  if (t == 0) { bbase[NB] = N_EDGES; rowptr[N_NODES] = N_EDGES; }
}

// ---- GEMM: A in registers, W in LDS, full-row coalesced X stores ----
// X[rel][n][p] = sum_p' A[n][p'] * Wt[rel][k(p)][p']  (all dims permuted-consistent)
template <bool SCAT>
__global__ __launch_bounds__(256, 5) void k_gemm9(
    const unsigned short* __restrict__ A,   // [N][128] bf16 (permuted cols)
    const unsigned short* __restrict__ Bw,  // [9][128][128] bf16 (k x perm-d)
    unsigned short* __restrict__ X,         // [9][N][128] bf16 (permuted cols)
    const int* __restrict__ src, const int* __restrict__ dst,
    const int* __restrict__ et, const int* __restrict__ curL,
    const int* __restrict__ bbase, unsigned* __restrict__ tmp) {
  __shared__ unsigned char Ws[32768];   // 128 rows x 256B (swizzled)
  const int t = threadIdx.x;
  if (SCAT && blockIdx.x >= NMB) {      // chunk-local scatter role
    int* off2 = (int*)Ws;               // overlay LDS
    const int c = blockIdx.x - NMB;
    if (t < NB) off2[t] = curL[t * NCH + c] + bbase[t];
    __syncthreads();
    int base = c * CHUNK;
    #pragma unroll 4
    for (int i = t; i < CHUNK; i += 256) {
      int e = base + i;
      if (e < N_EDGES) {
        int d = dst[e];
        int pos = atomicAdd(&off2[d >> 8], 1);
        tmp[pos] = ((unsigned)(d & 255) << 19) | ((unsigned)et[e] << 16) | (unsigned)src[e];
      }
    }
    return;
  }
  const int mb = blockIdx.x;
  const int wid = t >> 6, lane = t & 63;
  const int lr = lane & 15, kg = (lane >> 4) * 8;
  const int rAg = mb * 64 + wid * 16 + lr;     // A row this lane reads
  const bool rok = rAg < N_NODES;
  const unsigned short* Arow = A + (size_t)(rok ? rAg : 0) * 128;
  // hoist A fragments into registers ONCE (rel-invariant): 16 VGPRs
  s16x8 a[4];
  #pragma unroll
  for (int kk = 0; kk < 4; ++kk) {
    s16x8 v = (s16x8)(short)0;
    if (rok) v = *(const s16x8*)(Arow + kk * 32 + kg);
    a[kk] = v;
  }
  for (int rel = 0; rel < 9; ++rel) {
    // stage W_rel (32KB), swizzled
    const unsigned char* Bsrc = (const unsigned char*)(Bw + (size_t)rel * 16384);
    #pragma unroll
    for (int c = 0; c < 8; ++c) {
      int off = c * 4096 + t * 16;
      int row = off >> 8, ib = off & 255;
      *(u32x4*)(Ws + row * 256 + (ib ^ ((row & 7) << 4))) = *(const u32x4*)(Bsrc + off);
    }
    __syncthreads();
    f32x4 acc[8];
    #pragma unroll
    for (int n = 0; n < 8; ++n) acc[n] = (f32x4)(0.f);
    #pragma unroll
    for (int kk = 0; kk < 4; ++kk) {
      const int kb = (kk * 32 + kg) * 2;
      #pragma unroll
      for (int n = 0; n < 8; ++n) {
        int cc = n * 16 + lr;
        s16x8 b = *(const s16x8*)(Ws + cc * 256 + (kb ^ ((cc & 7) << 4)));
        acc[n] = __builtin_amdgcn_mfma_f32_16x16x32_bf16(a[kk], b, acc[n], 0, 0, 0);
      }
    }
    // epilogue: lane's 8 outputs (natural cols 16n+lr, n=0..7) pack into one
    // 16B chunk at permuted positions lr*8..lr*8+7 -> one full-line store per
    // row j (4 x 256B rows per instruction across the wave)
    #pragma unroll
    for (int j = 0; j < 4; ++j) {
      int grow = mb * 64 + wid * 16 + (lane >> 4) * 4 + j;
      if (grow < N_NODES) {
        u32x4 pk;
        pk.x = (unsigned)f2bf(acc[0][j]) | ((unsigned)f2bf(acc[1][j]) << 16);
        pk.y = (unsigned)f2bf(acc[2][j]) | ((unsigned)f2bf(acc[3][j]) << 16);
        pk.z = (unsigned)f2bf(acc[4][j]) | ((unsigned)f2bf(acc[5][j]) << 16);
        pk.w = (unsigned)f2bf(acc[6][j]) | ((unsigned)f2bf(acc[7][j]) << 16);
        *(u32x4*)((unsigned char*)X + ((size_t)rel * N_NODES + grow) * 256 + lr * 16) = pk;
      }
    }
    __syncthreads();   // all waves done with Ws before restage
  }
}

// ---- CSR finalize: per-node counting sort -> rowptr + u32 keys (et*N+src) ----
__global__ void k_bucket_finalize(const unsigned* __restrict__ tmp,
                                  const int* __restrict__ bbase,
                                  int* __restrict__ rowptr,
                                  unsigned* __restrict__ keys) {
  __shared__ int cnt[256];
  __shared__ int off[256];
  const int b = blockIdx.x;
  const int t = threadIdx.x;
  const int s = bbase[b], e = bbase[b + 1];
  cnt[t] = 0;
  __syncthreads();
  for (int i = s + t; i < e; i += 256)
    atomicAdd(&cnt[(tmp[i] >> 19) & 255u], 1);
  __syncthreads();
  int ex = block_scan_excl(cnt[t], t);
  int node = b * 256 + t;
  if (node < N_NODES) rowptr[node] = s + ex;
  off[t] = s + ex;
  __syncthreads();
  for (int i = s + t; i < e; i += 256) {
    unsigned r = tmp[i];
    int pos = atomicAdd(&off[(r >> 19) & 255u], 1);
    keys[pos] = ((r >> 16) & 7u) * N_NODES + (r & 0xffffu);
  }
}

// ---- per-node aggregation over CSR (permuted cols), 16-deep unroll ----
// lane L sums permuted positions 2L,2L+1; biasP is position-indexed.
// LAST: un-permute through a small LDS bounce, then contiguous f32 store.
template <bool LAST>
__global__ void k_aggregate(const unsigned short* __restrict__ X,
                            const unsigned* __restrict__ keys,
                            const int* __restrict__ rowptr,
                            const float* __restrict__ biasP,
                            void* __restrict__ out) {
  __shared__ float ob[4][128];
  const int t = threadIdx.x;
  const int w = t >> 6;
  const int v = blockIdx.x * 4 + w;
  const int lane = t & 63;
  const int start = rowptr[v], end = rowptr[v + 1];
  const unsigned char* Xb = (const unsigned char*)X;
  float a0 = 0.f, a1 = 0.f;
  int e = start;
  const int n16 = start + ((end - start) & ~15);
  for (; e < n16; e += 16) {
    unsigned kk[16], pp[16];
    #pragma unroll
    for (int q = 0; q < 16; ++q) kk[q] = keys[e + q];
    #pragma unroll
    for (int q = 0; q < 16; ++q)
      pp[q] = *(const unsigned*)(Xb + ((size_t)kk[q] << 8) + lane * 4);
    #pragma unroll
    for (int q = 0; q < 16; ++q) {
      a0 += __uint_as_float(pp[q] << 16);
      a1 += __uint_as_float(pp[q] & 0xffff0000u);
    }
  }
  const int n4 = start + ((end - start) & ~3);
  for (; e < n4; e += 4) {
    unsigned kk[4], pp[4];
    #pragma unroll
    for (int q = 0; q < 4; ++q) kk[q] = keys[e + q];
    #pragma unroll
    for (int q = 0; q < 4; ++q)
      pp[q] = *(const unsigned*)(Xb + ((size_t)kk[q] << 8) + lane * 4);
    #pragma unroll
    for (int q = 0; q < 4; ++q) {
      a0 += __uint_as_float(pp[q] << 16);
      a1 += __uint_as_float(pp[q] & 0xffff0000u);
    }
  }
  for (; e < end; ++e) {
    unsigned k0 = keys[e];
    unsigned p0 = *(const unsigned*)(Xb + ((size_t)k0 << 8) + lane * 4);
    a0 += __uint_as_float(p0 << 16); a1 += __uint_as_float(p0 & 0xffff0000u);
  }
  { // self-loop pseudo-relation row
    unsigned p = *(const unsigned*)(Xb + (((size_t)8 * N_NODES + v) << 8) + lane * 4);
    a0 += __uint_as_float(p << 16); a1 += __uint_as_float(p & 0xffff0000u);
  }
  const float2 bb = *(const float2*)(biasP + lane * 2);
  a0 += bb.x; a1 += bb.y;
  if (LAST) {
    // un-permute: position 2L -> natural col c0, 2L+1 -> c0+16
    int c0 = ((2 * lane) & 7) * 16 + (lane >> 2);
    ob[w][c0] = a0;
    ob[w][c0 + 16] = a1;
    __syncthreads();
    f32x2 o = *(const f32x2*)&ob[w][lane * 2];
    __builtin_nontemporal_store(o, (f32x2*)((float*)out + (size_t)v * 128 + lane * 2));
  } else {
    unsigned po = ((unsigned)f2bf(a1) << 16) | (unsigned)f2bf(a0);
    *(unsigned*)((unsigned short*)out + (size_t)v * 128 + lane * 2) = po;
  }
}

extern "C" void kernel_launch(void* const* d_in, const int* in_sizes, int n_in,
                              void* d_out, int out_size, void* d_ws, size_t ws_size,
                              hipStream_t stream) {
  const int*   nid  = (const int*)d_in[0];
  const int*   src  = (const int*)d_in[1];
  const int*   dst  = (const int*)d_in[2];
  const int*   et   = (const int*)d_in[3];
  const float* emb  = (const float*)d_in[4];
  const float* W    = (const float*)d_in[5];
  const float* Wl   = (const float*)d_in[6];
  const float* bias = (const float*)d_in[7];

  unsigned char* ws = (unsigned char*)d_ws;
  size_t off = 0;
  auto alloc = [&](size_t bytes) {
    void* p = ws + off;
    off = (off + bytes + 255) & ~(size_t)255;
    return p;
  };
  unsigned short* X    = (unsigned short*)alloc((size_t)9 * N_NODES * HID * 2);  // 115.2 MB
  unsigned short* h0   = (unsigned short*)alloc((size_t)N_NODES * HID * 2);      // 12.8 MB
  unsigned short* h1   = (unsigned short*)alloc((size_t)N_NODES * HID * 2);      // 12.8 MB
  unsigned short* Wt   = (unsigned short*)alloc((size_t)2 * 9 * 128 * 128 * 2);  // 0.6 MB
  unsigned*       keys = (unsigned*)alloc((size_t)N_EDGES * 4);                  // 6.4 MB
  int*            rowp = (int*)alloc((size_t)(N_NODES + 1) * 4);
  int*            histT= (int*)alloc((size_t)TOT * 4);                           // 150 KB
  int*            curL = (int*)alloc((size_t)TOT * 4);                           // 150 KB
  int*            btot = (int*)alloc((size_t)NB * 4);
  int*            bbas = (int*)alloc((size_t)(NB + 1) * 4);
  float*          biasP= (float*)alloc((size_t)2 * 128 * 4);
  // scatter tmp aliases h1 (dead until aggregate-L0)
  unsigned*       tmp  = (unsigned*)h1;

  k_pre<<<NGB + NCH + NCW + 1, 256, 0, stream>>>(nid, emb, h0, dst, histT, W, Wl, Wt,
                                                 bias, biasP);
  k_scan_buckets<<<NB, 64, 0, stream>>>(histT, curL, btot);
  k_scan_top<<<1, 256, 0, stream>>>(btot, bbas, rowp);
  // gemm layer 0 (782 blocks) + chunk_scatter (196 blocks) fused
  k_gemm9<true><<<NMB + NCH, 256, 0, stream>>>(h0, Wt, X, src, dst, et, curL, bbas, tmp);
  k_bucket_finalize<<<NB, 256, 0, stream>>>(tmp, bbas, rowp, keys);

  const int agrid = N_NODES / 4;                 // 12500, one wave per node
  k_aggregate<false><<<agrid, 256, 0, stream>>>(X, keys, rowp, biasP, (void*)h1);
  k_gemm9<false><<<NMB, 256, 0, stream>>>(h1, Wt + (size_t)9 * 128 * 128, X,
                                          src, dst, et, curL, bbas, tmp);
  k_aggregate<true><<<agrid, 256, 0, stream>>>(X, keys, rowp, biasP + HID, (void*)d_out);
}